// Round 1
// baseline (2350.123 us; speedup 1.0000x reference)
//
#include <hip/hip_runtime.h>
#include <float.h>
#include <math.h>

// ============================================================================
// BeamSearchDecoder — MI355X. Greedy-equivalence: h0 = repeat(enc_h,K) and
// scores0 = 0 make all K=3 beams identical; the 9 candidates per batch are
// [v0,v1,v2]x3 and top-3 = three copies of v0 regardless of tie-break, so
// every beam takes the argmax token forever. decoded = one-hot(greedy seq),
// h = final greedy h x3, scores = cumulative (max - logsumexp) x3.
//
// All logits math fp32 (argmax decisions must track the fp32 numpy ref).
//
// R8 vs R7 (1940): kill the split-K lpart round-trip (32.8 MB write + 32.8 MB
// read per step ~ 2.1 GB total) and the k_combine launch. Full-K fused GEMV:
// grid = 125 v-chunks (256 cols) x 4 row-groups (8 rows) = 500 blocks
// (2/CU, 8 waves/CU). Each thread: 1 col, acc[8] over K=512, 8-deep w
// prefetch; per-block online max/argmax/sumexp -> tiny pm/ps/pidx[32][128].
// Wt (65.5 MB) is LLC-resident across steps; XCD swizzle (bid = slot*8 +
// vb%8) co-locates the 4 same-vb row-group blocks on one XCD so the 512 KB
// Wt slice is L2-served. GRU select widens 63 -> 125 chunks (2 per lane).
// ============================================================================

#define BB 32
#define HH 512
#define EE 256
#define VV 32000
#define TSTEPS 32
#define NCH 125                              // 256-col chunks (exact: 125*256)
#define PSTR 128                             // pm/ps/pidx row stride
#define DEC_ELEMS (BB * (TSTEPS + 1) * VV)   // 33,792,000
#define H_ELEMS (BB * 3 * HH)                // 49,152

// ---------------------------------------------------------------------------
// Setup: tiled transpose W_out (V,H) -> Wt_out (H,V)
// ---------------------------------------------------------------------------
__global__ __launch_bounds__(256) void k_transpose_out(
    const float* __restrict__ W, float* __restrict__ Wt) {
  __shared__ float t[32][33];
  const int vb = blockIdx.x * 32;  // 1000
  const int kb = blockIdx.y * 32;  // 16
  const int c = threadIdx.x & 31, rq = threadIdx.x >> 5;
#pragma unroll
  for (int i = 0; i < 4; ++i) {
    int r = rq + i * 8;
    t[r][c] = W[(size_t)(vb + r) * HH + kb + c];
  }
  __syncthreads();
#pragma unroll
  for (int i = 0; i < 4; ++i) {
    int r = rq + i * 8;
    Wt[(size_t)(kb + r) * VV + vb + c] = t[c][r];
  }
}

// ---------------------------------------------------------------------------
// Setup: h0 = encoder_hidden, scores = 0, seq col 0 = START(=1)
// ---------------------------------------------------------------------------
__global__ __launch_bounds__(256) void k_init(
    const float* __restrict__ enc_h, float* __restrict__ hb0,
    float* __restrict__ scores, int* __restrict__ tok_seq) {
  int idx = blockIdx.x * 256 + threadIdx.x;  // 64*256
  if (idx < BB * HH) hb0[idx] = enc_h[idx];
  if (idx < BB) { scores[idx] = 0.0f; tok_seq[idx] = 1; }
}

// ---------------------------------------------------------------------------
// Fused full-K logits GEMV + per-chunk selection stats.
// Grid 512 (swizzled): xcd = bid&7, slot = bid>>3, rg = slot&3,
// vb = (slot>>2)*8 + xcd; vb >= 125 -> dead block (12 of them).
// Block 256 thr: thread = col vb*256+tid, 8 row-accumulators (rows rg*8..+8),
// K=512 full. h rows in LDS (broadcast b128 reads, 8 FMA per 2xb128 per row
// group step). Writes per-(row, chunk) max / argmax(low idx) / sum exp(l-max).
// No partial-logits buffer, no combine kernel.
// ---------------------------------------------------------------------------
__global__ __launch_bounds__(256) void k_gemv_fused(
    const float* __restrict__ Wt,    // (H, V)
    const float* __restrict__ hmat,  // (B, H)
    const float* __restrict__ bout,  // (V,)
    float* __restrict__ pm, float* __restrict__ ps, int* __restrict__ pidx) {
  const int bid = blockIdx.x;
  const int xcd = bid & 7, slot = bid >> 3;
  const int rg = slot & 3;
  const int vb = (slot >> 2) * 8 + xcd;
  if (vb >= NCH) return;
  const int tid = threadIdx.x;

  __shared__ float hs[8][HH];  // 16 KB: rows rg*8 .. rg*8+7
  {
    const float4* hp = (const float4*)(hmat + (size_t)rg * 8 * HH);
    float4* hd = (float4*)hs;
#pragma unroll
    for (int i = 0; i < 4; ++i) hd[tid + i * 256] = hp[tid + i * 256];
  }
  __syncthreads();

  const int col = vb * 256 + tid;  // < 32000 always
  const float* wp = Wt + col;

  float acc[8];
#pragma unroll
  for (int r = 0; r < 8; ++r) acc[r] = 0.0f;

  float wc[8];
#pragma unroll
  for (int kk = 0; kk < 8; ++kk) wc[kk] = wp[(size_t)kk * VV];

  for (int k0 = 0; k0 < HH; k0 += 8) {
    float wn[8];
    const bool more = (k0 + 8 < HH);
    if (more) {
      const float* np = wp + (size_t)(k0 + 8) * VV;
#pragma unroll
      for (int kk = 0; kk < 8; ++kk) wn[kk] = np[(size_t)kk * VV];
    }
#pragma unroll
    for (int r = 0; r < 8; ++r) {
      const float4 a = *(const float4*)&hs[r][k0];
      const float4 b = *(const float4*)&hs[r][k0 + 4];
      acc[r] = fmaf(a.x, wc[0], acc[r]);
      acc[r] = fmaf(a.y, wc[1], acc[r]);
      acc[r] = fmaf(a.z, wc[2], acc[r]);
      acc[r] = fmaf(a.w, wc[3], acc[r]);
      acc[r] = fmaf(b.x, wc[4], acc[r]);
      acc[r] = fmaf(b.y, wc[5], acc[r]);
      acc[r] = fmaf(b.z, wc[6], acc[r]);
      acc[r] = fmaf(b.w, wc[7], acc[r]);
    }
    if (more) {
#pragma unroll
      for (int kk = 0; kk < 8; ++kk) wc[kk] = wn[kk];
    }
  }

  const float bo = bout[col];
#pragma unroll
  for (int r = 0; r < 8; ++r) acc[r] += bo;

  // ---- per-row block reduction: max/argmax then sum exp(l - max) ----
  const int lane = tid & 63, wv = tid >> 6;
  __shared__ float wm[8][4];
  __shared__ int wi[8][4];
  __shared__ float wsm[8][4];

#pragma unroll
  for (int r = 0; r < 8; ++r) {
    float tm = acc[r];
    int ti = col;
#pragma unroll
    for (int off = 1; off < 64; off <<= 1) {
      const float om = __shfl_xor(tm, off);
      const int oi = __shfl_xor(ti, off);
      if (om > tm || (om == tm && oi < ti)) { tm = om; ti = oi; }
    }
    if (lane == 0) { wm[r][wv] = tm; wi[r][wv] = ti; }
  }
  __syncthreads();

  float M[8];
#pragma unroll
  for (int r = 0; r < 8; ++r) {
    const float m0 = fmaxf(wm[r][0], wm[r][1]);
    const float m1 = fmaxf(wm[r][2], wm[r][3]);
    M[r] = fmaxf(m0, m1);
  }
#pragma unroll
  for (int r = 0; r < 8; ++r) {
    float e = __expf(acc[r] - M[r]);
#pragma unroll
    for (int off = 1; off < 64; off <<= 1) e += __shfl_xor(e, off);
    if (lane == 0) wsm[r][wv] = e;
  }
  __syncthreads();

  if (tid < 8) {
    const int r = tid;
    const int grow = rg * 8 + r;
    float bmv = wm[r][0];
    int bix = wi[r][0];
#pragma unroll
    for (int w = 1; w < 4; ++w) {
      if (wm[r][w] > bmv || (wm[r][w] == bmv && wi[r][w] < bix)) {
        bmv = wm[r][w];
        bix = wi[r][w];
      }
    }
    pm[grow * PSTR + vb] = bmv;
    ps[grow * PSTR + vb] = wsm[r][0] + wsm[r][1] + wsm[r][2] + wsm[r][3];
    pidx[grow * PSTR + vb] = bix;
  }
}

// ---------------------------------------------------------------------------
// GRU step with fused token-select prologue. Grid 128 = (rg 0..7 of 4 rows) x
// (jt 0..15 of 32 H-cols). Block 256 thr. Native-layout W_ih/W_hh reads.
// step==TSTEPS: select only. Select reduces 125 chunk-partials: lane merges
// chunks lane and lane+64 (both stored relative to their own chunk max).
// ---------------------------------------------------------------------------
__global__ __launch_bounds__(256) void k_gru(
    const int step,
    const float* __restrict__ emb,
    const float* __restrict__ W_ih,   // (1536, 256) native
    const float* __restrict__ W_hh,   // (1536, 512) native
    const float* __restrict__ b_ih, const float* __restrict__ b_hh,
    const float* __restrict__ hin, float* __restrict__ hout,
    const float* __restrict__ pm, const float* __restrict__ ps,
    const int* __restrict__ pidx,
    float* __restrict__ scores, int* __restrict__ tok_seq) {
  const int tid = threadIdx.x;
  const int rg = blockIdx.x >> 4;   // 0..7
  const int jt = blockIdx.x & 15;   // 0..15
  const int r0 = rg * 4, j0 = jt * 32;
  const int lane = tid & 63, wv = tid >> 6;  // wv 0..3

  __shared__ int toks[4];
  __shared__ float xs[4][EE];
  __shared__ float hsm[4][HH];
  __shared__ float gpart[24 * 272];

  // ---- select: reduce 125 chunk-partials for row r0+wv ----
  if (step == 0) {
    if (tid < 4) toks[tid] = 1;  // START
  } else {
    const int row = r0 + wv;
    const float m1 = pm[row * PSTR + lane];        // lane < 64 <= NCH: valid
    const float s1 = ps[row * PSTR + lane];
    const int i1 = pidx[row * PSTR + lane];
    const bool c2 = (lane + 64 < NCH);
    const float m2 = c2 ? pm[row * PSTR + lane + 64] : -FLT_MAX;
    const float s2 = c2 ? ps[row * PSTR + lane + 64] : 0.0f;
    const int i2 = c2 ? pidx[row * PSTR + lane + 64] : 0x7fffffff;
    // merged per-lane argmax candidate (chunk1 cols < chunk2 cols: tie -> 1)
    float gm;
    int gi;
    if (m2 > m1) { gm = m2; gi = i2; } else { gm = m1; gi = i1; }
#pragma unroll
    for (int off = 1; off < 64; off <<= 1) {
      const float om = __shfl_xor(gm, off);
      const int oi = __shfl_xor(gi, off);
      if (om > gm || (om == gm && oi < gi)) { gm = om; gi = oi; }
    }
    float term = s1 * __expf(m1 - gm) + (c2 ? s2 * __expf(m2 - gm) : 0.0f);
#pragma unroll
    for (int off = 1; off < 64; off <<= 1) term += __shfl_xor(term, off);
    if (lane == 0) {
      toks[wv] = gi;
      if (jt == 0) {
        scores[row] -= logf(term);      // += max - logsumexp
        tok_seq[step * BB + row] = gi;  // seq column `step`
      }
    }
  }
  __syncthreads();
  if (step == TSTEPS) return;

  // ---- stage x = relu(emb[tok]) and h_prev ----
  for (int i = tid; i < 4 * EE; i += 256) {
    const int r = i >> 8, c = i & (EE - 1);
    const float e = emb[(size_t)toks[r] * EE + c];
    xs[r][c] = e > 0.0f ? e : 0.0f;
  }
  for (int i = tid; i < 4 * HH; i += 256) {
    const int r = i >> 9, c = i & (HH - 1);
    hsm[r][c] = hin[(r0 + r) * HH + c];
  }
  __syncthreads();

  const int jh = tid & 31, kq = tid >> 5;  // 32 cols x 8 k-slices
  const int j = j0 + jh;
  float ai[3][4], ah[3][4];
#pragma unroll
  for (int g = 0; g < 3; ++g)
#pragma unroll
    for (int r = 0; r < 4; ++r) { ai[g][r] = 0.0f; ah[g][r] = 0.0f; }

#pragma unroll 2
  for (int q = 0; q < 8; ++q) {
    const int k4 = kq * 32 + q * 4;
    float4 xr[4];
#pragma unroll
    for (int r = 0; r < 4; ++r) xr[r] = *(const float4*)&xs[r][k4];
#pragma unroll
    for (int g = 0; g < 3; ++g) {
      const float4 w = *(const float4*)&W_ih[(size_t)(g * HH + j) * EE + k4];
#pragma unroll
      for (int r = 0; r < 4; ++r) {
        ai[g][r] = fmaf(xr[r].x, w.x, ai[g][r]);
        ai[g][r] = fmaf(xr[r].y, w.y, ai[g][r]);
        ai[g][r] = fmaf(xr[r].z, w.z, ai[g][r]);
        ai[g][r] = fmaf(xr[r].w, w.w, ai[g][r]);
      }
    }
  }
#pragma unroll 2
  for (int q = 0; q < 16; ++q) {
    const int k4 = kq * 64 + q * 4;
    float4 hr[4];
#pragma unroll
    for (int r = 0; r < 4; ++r) hr[r] = *(const float4*)&hsm[r][k4];
#pragma unroll
    for (int g = 0; g < 3; ++g) {
      const float4 w = *(const float4*)&W_hh[(size_t)(g * HH + j) * HH + k4];
#pragma unroll
      for (int r = 0; r < 4; ++r) {
        ah[g][r] = fmaf(hr[r].x, w.x, ah[g][r]);
        ah[g][r] = fmaf(hr[r].y, w.y, ah[g][r]);
        ah[g][r] = fmaf(hr[r].z, w.z, ah[g][r]);
        ah[g][r] = fmaf(hr[r].w, w.w, ah[g][r]);
      }
    }
  }
  {
    const int base = kq * 34 + jh;
#pragma unroll
    for (int g = 0; g < 3; ++g)
#pragma unroll
      for (int r = 0; r < 4; ++r) {
        gpart[(g * 4 + r) * 272 + base] = ai[g][r];
        gpart[(12 + g * 4 + r) * 272 + base] = ah[g][r];
      }
  }
  __syncthreads();

  if (tid < 128) {
    const int r = tid >> 5, jh2 = tid & 31;
    const int j2 = j0 + jh2;
    float g6[6];
#pragma unroll
    for (int c = 0; c < 6; ++c) {
      const int cc = (c < 3) ? (c * 4 + r) : (12 + (c - 3) * 4 + r);
      float s = 0.0f;
#pragma unroll
      for (int q = 0; q < 8; ++q) s += gpart[cc * 272 + q * 34 + jh2];
      g6[c] = s;
    }
    const float ir = g6[0] + b_ih[j2];
    const float iz = g6[1] + b_ih[HH + j2];
    const float in_ = g6[2] + b_ih[2 * HH + j2];
    const float hr_ = g6[3] + b_hh[j2];
    const float hz = g6[4] + b_hh[HH + j2];
    const float hn = g6[5] + b_hh[2 * HH + j2];
    const float rr = 1.0f / (1.0f + expf(-(ir + hr_)));
    const float zz = 1.0f / (1.0f + expf(-(iz + hz)));
    const float nn = tanhf(in_ + rr * hn);
    hout[(r0 + r) * HH + j2] = (1.0f - zz) * nn + zz * hsm[r][j2];
  }
}

// ---------------------------------------------------------------------------
// Full-output writer: one-hot rows composed inline (no memset), h x3,
// scores x3. All stores float4, coalesced.
// ---------------------------------------------------------------------------
__global__ __launch_bounds__(256) void k_out(
    const int* __restrict__ tok_seq, const float* __restrict__ hfin,
    const float* __restrict__ scores, float* __restrict__ out) {
  const int blk = blockIdx.x, tid = threadIdx.x;
  if (blk < BB * (TSTEPS + 1)) {           // one (b,t) one-hot row
    const int b = blk / (TSTEPS + 1), t = blk % (TSTEPS + 1);
    const int tok = tok_seq[t * BB + b];
    const int tq = tok >> 2, tl = tok & 3;
    float4* op = (float4*)(out + (size_t)blk * VV);
    for (int i = tid; i < VV / 4; i += 256) {
      float4 z = {0.0f, 0.0f, 0.0f, 0.0f};
      if (i == tq) (&z.x)[tl] = 1.0f;
      op[i] = z;
    }
  } else if (blk < BB * (TSTEPS + 1) + 12) {  // h x3: 12288 float4
#pragma unroll
    for (int it = 0; it < 4; ++it) {
      const int idx = (blk - BB * (TSTEPS + 1)) * 1024 + it * 256 + tid;
      if (idx < H_ELEMS / 4) {
        const int fi = idx * 4;
        const int b = fi / (3 * HH);
        const int j0 = (fi % (3 * HH)) % HH;
        ((float4*)(out + DEC_ELEMS))[idx] =
            *(const float4*)(hfin + b * HH + j0);
      }
    }
  } else {                                   // scores x3: 96 floats
    if (tid < BB * 3) {
      out[(size_t)DEC_ELEMS + H_ELEMS + tid] = scores[tid / 3];
    }
  }
}

// ---------------------------------------------------------------------------
extern "C" void kernel_launch(void* const* d_in, const int* in_sizes, int n_in,
                              void* d_out, int out_size, void* d_ws, size_t ws_size,
                              hipStream_t stream) {
  const float* enc_h = (const float*)d_in[1];
  const float* emb   = (const float*)d_in[2];
  const float* W_ih  = (const float*)d_in[3];
  const float* W_hh  = (const float*)d_in[4];
  const float* b_ih  = (const float*)d_in[5];
  const float* b_hh  = (const float*)d_in[6];
  const float* W_out = (const float*)d_in[7];
  const float* b_out = (const float*)d_in[8];
  float* out = (float*)d_out;

  // workspace layout (floats) — no lpart anymore (~65.7 MB total)
  float* ws = (float*)d_ws;
  float* Wt_out  = ws;                       // 16,384,000
  float* hb0     = Wt_out + 16384000;        // 16,384
  float* hb1     = hb0 + BB * HH;            // 16,384
  float* pm      = hb1 + BB * HH;            // 32*128
  float* ps      = pm + BB * PSTR;           // 32*128
  float* scores  = ps + BB * PSTR;           // 32
  int*   pidx    = (int*)(scores + BB);      // 32*128
  int*   tok_seq = pidx + BB * PSTR;         // 33*32

  k_transpose_out<<<dim3(1000, 16), 256, 0, stream>>>(W_out, Wt_out);
  k_init<<<64, 256, 0, stream>>>(enc_h, hb0, scores, tok_seq);

  for (int t = 0; t < TSTEPS; ++t) {
    float* hin  = (t & 1) ? hb1 : hb0;
    float* hout = (t & 1) ? hb0 : hb1;
    k_gru<<<128, 256, 0, stream>>>(t, emb, W_ih, W_hh, b_ih, b_hh,
                                   hin, hout, pm, ps, pidx, scores, tok_seq);
    k_gemv_fused<<<512, 256, 0, stream>>>(Wt_out, hout, b_out, pm, ps, pidx);
  }
  // final selection: seq col 32 + last score term
  k_gru<<<128, 256, 0, stream>>>(TSTEPS, emb, W_ih, W_hh, b_ih, b_hh,
                                 hb0, hb1, pm, ps, pidx, scores, tok_seq);
  // final h lives in hb0 (t=31 odd: hout=hb0); full-output writer
  k_out<<<BB * (TSTEPS + 1) + 13, 256, 0, stream>>>(tok_seq, hb0, scores, out);
}

// Round 2
// 1905.683 us; speedup vs baseline: 1.2332x; 1.2332x over previous
//
#include <hip/hip_runtime.h>
#include <float.h>
#include <math.h>

// ============================================================================
// BeamSearchDecoder — MI355X. Greedy-equivalence: h0 = repeat(enc_h,K) and
// scores0 = 0 make all K=3 beams identical; the 9 candidates per batch are
// [v0,v1,v2]x3 and top-3 = three copies of v0 regardless of tie-break, so
// every beam takes the argmax token forever. decoded = one-hot(greedy seq),
// h = final greedy h x3, scores = cumulative (max - logsumexp) x3.
//
// All logits math fp32 (argmax decisions must track the fp32 numpy ref).
//
// R9 vs R8 (2350, REGRESSION): R8's fused gemv had 8 FMA/load (latency-bound)
// and 4x Wt read amplification across row-group blocks. R9 keeps the fusion
// (no lpart, no combine kernel — R8's win) but fixes geometry: 500 blocks
// PARTITION columns (64 cols each) so Wt is read ONCE per step; thread =
// 4 cols (float4 W loads) x 2 rows -> 64 FMA per 8 b128 loads per 8-k group;
// depth-3 load pipeline (A/B/C, static indices) covers ~512 cyc LLC latency
// at 2 waves/SIMD. All 32 rows staged in hs[32][516] (pad -> conflict-free);
// per-row stats reduce within one 16-lane shfl group.
// ============================================================================

#define BB 32
#define HH 512
#define EE 256
#define VV 32000
#define TSTEPS 32
#define NCH 500                              // 64-col chunks (exact: 500*64)
#define PSTR 512                             // pm/ps/pidx row stride
#define DEC_ELEMS (BB * (TSTEPS + 1) * VV)   // 33,792,000
#define H_ELEMS (BB * 3 * HH)                // 49,152

// ---------------------------------------------------------------------------
// Setup: tiled transpose W_out (V,H) -> Wt_out (H,V)
// ---------------------------------------------------------------------------
__global__ __launch_bounds__(256) void k_transpose_out(
    const float* __restrict__ W, float* __restrict__ Wt) {
  __shared__ float t[32][33];
  const int vb = blockIdx.x * 32;  // 1000
  const int kb = blockIdx.y * 32;  // 16
  const int c = threadIdx.x & 31, rq = threadIdx.x >> 5;
#pragma unroll
  for (int i = 0; i < 4; ++i) {
    int r = rq + i * 8;
    t[r][c] = W[(size_t)(vb + r) * HH + kb + c];
  }
  __syncthreads();
#pragma unroll
  for (int i = 0; i < 4; ++i) {
    int r = rq + i * 8;
    Wt[(size_t)(kb + r) * VV + vb + c] = t[c][r];
  }
}

// ---------------------------------------------------------------------------
// Setup: h0 = encoder_hidden, scores = 0, seq col 0 = START(=1)
// ---------------------------------------------------------------------------
__global__ __launch_bounds__(256) void k_init(
    const float* __restrict__ enc_h, float* __restrict__ hb0,
    float* __restrict__ scores, int* __restrict__ tok_seq) {
  int idx = blockIdx.x * 256 + threadIdx.x;  // 64*256
  if (idx < BB * HH) hb0[idx] = enc_h[idx];
  if (idx < BB) { scores[idx] = 0.0f; tok_seq[idx] = 1; }
}

// ---------------------------------------------------------------------------
// Fused full-K logits GEMV + per-chunk selection stats.
// Grid 500 = column chunks of 64 (Wt read exactly once per step).
// Block 256 thr: colq = tid&15 (4 cols via float4), rp = tid>>4 (rows 2rp,
// 2rp+1). Per 8-k group: 8 x b128 W loads + 64 FMA; depth-3 A/B/C pipeline.
// h (all 32 rows) in hs[32][516] (pad 4 -> row-pair stride = 8 banks,
// conflict-free). Per-row max/argmax/sumexp via 16-lane shfl group ->
// pm/ps/pidx[32][512]. No partial-logits buffer, no combine kernel.
// ---------------------------------------------------------------------------
#define FMA4(accv, hscal, wv)              \
  accv.x = fmaf(hscal, wv.x, accv.x);      \
  accv.y = fmaf(hscal, wv.y, accv.y);      \
  accv.z = fmaf(hscal, wv.z, accv.z);      \
  accv.w = fmaf(hscal, wv.w, accv.w);

#define LOADG(W, g)                                                    \
  {                                                                    \
    const float* p_ = wp + (size_t)(g) * 8 * VV;                       \
    _Pragma("unroll") for (int j_ = 0; j_ < 8; ++j_)                   \
        W[j_] = *(const float4*)(p_ + (size_t)j_ * VV);                \
  }

#define COMPG(W, g)                                                    \
  {                                                                    \
    const int k0_ = (g) * 8;                                           \
    _Pragma("unroll") for (int jj_ = 0; jj_ < 2; ++jj_) {              \
      const float4 h0_ = *(const float4*)&hs[r0][k0_ + jj_ * 4];       \
      const float4 h1_ = *(const float4*)&hs[r0 + 1][k0_ + jj_ * 4];   \
      FMA4(acc0, h0_.x, W[jj_ * 4 + 0]);                               \
      FMA4(acc0, h0_.y, W[jj_ * 4 + 1]);                               \
      FMA4(acc0, h0_.z, W[jj_ * 4 + 2]);                               \
      FMA4(acc0, h0_.w, W[jj_ * 4 + 3]);                               \
      FMA4(acc1, h1_.x, W[jj_ * 4 + 0]);                               \
      FMA4(acc1, h1_.y, W[jj_ * 4 + 1]);                               \
      FMA4(acc1, h1_.z, W[jj_ * 4 + 2]);                               \
      FMA4(acc1, h1_.w, W[jj_ * 4 + 3]);                               \
    }                                                                  \
  }

__global__ __launch_bounds__(256) void k_gemv_fused(
    const float* __restrict__ Wt,    // (H, V)
    const float* __restrict__ hmat,  // (B, H)
    const float* __restrict__ bout,  // (V,)
    float* __restrict__ pm, float* __restrict__ ps, int* __restrict__ pidx) {
  const int vb = blockIdx.x;       // 0..499
  const int tid = threadIdx.x;
  const int colq = tid & 15;       // col quad within chunk
  const int rp = tid >> 4;         // 0..15 -> rows 2rp, 2rp+1
  const int r0 = rp * 2;
  const int col = vb * 64 + colq * 4;

  __shared__ float hs[32][516];    // 66 KB, padded
  {
    float4* hd = (float4*)hs;                 // row r -> float4 offset r*129
    const float4* hp = (const float4*)hmat;   // row r -> float4 offset r*128
#pragma unroll
    for (int i = 0; i < 16; ++i) {
      const int idx = i * 256 + tid;
      const int r = idx >> 7, q = idx & 127;
      hd[r * 129 + q] = hp[idx];
    }
  }
  __syncthreads();

  const float* wp = Wt + col;
  float4 acc0 = {0.0f, 0.0f, 0.0f, 0.0f};
  float4 acc1 = {0.0f, 0.0f, 0.0f, 0.0f};

  float4 A[8], B[8], C[8];
  LOADG(A, 0);
  LOADG(B, 1);
#pragma unroll 1
  for (int g = 0; g < 63; g += 3) {   // 64 groups of 8 k
    LOADG(C, g + 2);
    COMPG(A, g);
    if (g + 3 < 64) LOADG(A, g + 3);
    COMPG(B, g + 1);
    if (g + 4 < 64) LOADG(B, g + 4);
    COMPG(C, g + 2);
  }
  COMPG(A, 63);

  {
    const float4 bo = *(const float4*)(bout + col);
    acc0.x += bo.x; acc0.y += bo.y; acc0.z += bo.z; acc0.w += bo.w;
    acc1.x += bo.x; acc1.y += bo.y; acc1.z += bo.z; acc1.w += bo.w;
  }

  // ---- per-row stats within the 16-lane col group (strict > : low idx) ----
  const int lane = tid & 63;

  float m0 = acc0.x; int i0 = col;
  if (acc0.y > m0) { m0 = acc0.y; i0 = col + 1; }
  if (acc0.z > m0) { m0 = acc0.z; i0 = col + 2; }
  if (acc0.w > m0) { m0 = acc0.w; i0 = col + 3; }
  float m1 = acc1.x; int i1 = col;
  if (acc1.y > m1) { m1 = acc1.y; i1 = col + 1; }
  if (acc1.z > m1) { m1 = acc1.z; i1 = col + 2; }
  if (acc1.w > m1) { m1 = acc1.w; i1 = col + 3; }
#pragma unroll
  for (int off = 1; off < 16; off <<= 1) {
    const float om0 = __shfl_xor(m0, off);
    const int oi0 = __shfl_xor(i0, off);
    if (om0 > m0 || (om0 == m0 && oi0 < i0)) { m0 = om0; i0 = oi0; }
    const float om1 = __shfl_xor(m1, off);
    const int oi1 = __shfl_xor(i1, off);
    if (om1 > m1 || (om1 == m1 && oi1 < i1)) { m1 = om1; i1 = oi1; }
  }
  float s0 = __expf(acc0.x - m0) + __expf(acc0.y - m0) +
             __expf(acc0.z - m0) + __expf(acc0.w - m0);
  float s1 = __expf(acc1.x - m1) + __expf(acc1.y - m1) +
             __expf(acc1.z - m1) + __expf(acc1.w - m1);
#pragma unroll
  for (int off = 1; off < 16; off <<= 1) {
    s0 += __shfl_xor(s0, off);
    s1 += __shfl_xor(s1, off);
  }

  if ((lane & 15) == 0) {
    pm[r0 * PSTR + vb] = m0;
    ps[r0 * PSTR + vb] = s0;
    pidx[r0 * PSTR + vb] = i0;
    pm[(r0 + 1) * PSTR + vb] = m1;
    ps[(r0 + 1) * PSTR + vb] = s1;
    pidx[(r0 + 1) * PSTR + vb] = i1;
  }
}

// ---------------------------------------------------------------------------
// GRU step with fused token-select prologue. Grid 128 = (rg 0..7 of 4 rows) x
// (jt 0..15 of 32 H-cols). Block 256 thr. Native-layout W_ih/W_hh reads.
// step==TSTEPS: select only. Select reduces 500 chunk-partials: lane j holds
// chunks lane+64j (j=0..7), local merge then 64-lane shfl tree.
// ---------------------------------------------------------------------------
__global__ __launch_bounds__(256) void k_gru(
    const int step,
    const float* __restrict__ emb,
    const float* __restrict__ W_ih,   // (1536, 256) native
    const float* __restrict__ W_hh,   // (1536, 512) native
    const float* __restrict__ b_ih, const float* __restrict__ b_hh,
    const float* __restrict__ hin, float* __restrict__ hout,
    const float* __restrict__ pm, const float* __restrict__ ps,
    const int* __restrict__ pidx,
    float* __restrict__ scores, int* __restrict__ tok_seq) {
  const int tid = threadIdx.x;
  const int rg = blockIdx.x >> 4;   // 0..7
  const int jt = blockIdx.x & 15;   // 0..15
  const int r0 = rg * 4, j0 = jt * 32;
  const int lane = tid & 63, wv = tid >> 6;  // wv 0..3

  __shared__ int toks[4];
  __shared__ float xs[4][EE];
  __shared__ float hsm[4][HH];
  __shared__ float gpart[24 * 272];

  // ---- select: reduce 500 chunk-partials for row r0+wv ----
  if (step == 0) {
    if (tid < 4) toks[tid] = 1;  // START
  } else {
    const int row = r0 + wv;
    float mv[8], sv[8];
    int iv[8];
#pragma unroll
    for (int j = 0; j < 8; ++j) {
      const int ch = lane + 64 * j;
      const bool v = (ch < NCH);
      mv[j] = v ? pm[row * PSTR + ch] : -FLT_MAX;
      sv[j] = v ? ps[row * PSTR + ch] : 0.0f;
      iv[j] = v ? pidx[row * PSTR + ch] : 0x7fffffff;
    }
    float gm = mv[0];
    int gi = iv[0];
#pragma unroll
    for (int j = 1; j < 8; ++j)
      if (mv[j] > gm || (mv[j] == gm && iv[j] < gi)) { gm = mv[j]; gi = iv[j]; }
#pragma unroll
    for (int off = 1; off < 64; off <<= 1) {
      const float om = __shfl_xor(gm, off);
      const int oi = __shfl_xor(gi, off);
      if (om > gm || (om == gm && oi < gi)) { gm = om; gi = oi; }
    }
    float term = 0.0f;
#pragma unroll
    for (int j = 0; j < 8; ++j) term += sv[j] * __expf(mv[j] - gm);
#pragma unroll
    for (int off = 1; off < 64; off <<= 1) term += __shfl_xor(term, off);
    if (lane == 0) {
      toks[wv] = gi;
      if (jt == 0) {
        scores[row] -= logf(term);      // += max - logsumexp
        tok_seq[step * BB + row] = gi;  // seq column `step`
      }
    }
  }
  __syncthreads();
  if (step == TSTEPS) return;

  // ---- stage x = relu(emb[tok]) and h_prev ----
  for (int i = tid; i < 4 * EE; i += 256) {
    const int r = i >> 8, c = i & (EE - 1);
    const float e = emb[(size_t)toks[r] * EE + c];
    xs[r][c] = e > 0.0f ? e : 0.0f;
  }
  for (int i = tid; i < 4 * HH; i += 256) {
    const int r = i >> 9, c = i & (HH - 1);
    hsm[r][c] = hin[(r0 + r) * HH + c];
  }
  __syncthreads();

  const int jh = tid & 31, kq = tid >> 5;  // 32 cols x 8 k-slices
  const int j = j0 + jh;
  float ai[3][4], ah[3][4];
#pragma unroll
  for (int g = 0; g < 3; ++g)
#pragma unroll
    for (int r = 0; r < 4; ++r) { ai[g][r] = 0.0f; ah[g][r] = 0.0f; }

#pragma unroll 2
  for (int q = 0; q < 8; ++q) {
    const int k4 = kq * 32 + q * 4;
    float4 xr[4];
#pragma unroll
    for (int r = 0; r < 4; ++r) xr[r] = *(const float4*)&xs[r][k4];
#pragma unroll
    for (int g = 0; g < 3; ++g) {
      const float4 w = *(const float4*)&W_ih[(size_t)(g * HH + j) * EE + k4];
#pragma unroll
      for (int r = 0; r < 4; ++r) {
        ai[g][r] = fmaf(xr[r].x, w.x, ai[g][r]);
        ai[g][r] = fmaf(xr[r].y, w.y, ai[g][r]);
        ai[g][r] = fmaf(xr[r].z, w.z, ai[g][r]);
        ai[g][r] = fmaf(xr[r].w, w.w, ai[g][r]);
      }
    }
  }
#pragma unroll 2
  for (int q = 0; q < 16; ++q) {
    const int k4 = kq * 64 + q * 4;
    float4 hr[4];
#pragma unroll
    for (int r = 0; r < 4; ++r) hr[r] = *(const float4*)&hsm[r][k4];
#pragma unroll
    for (int g = 0; g < 3; ++g) {
      const float4 w = *(const float4*)&W_hh[(size_t)(g * HH + j) * HH + k4];
#pragma unroll
      for (int r = 0; r < 4; ++r) {
        ah[g][r] = fmaf(hr[r].x, w.x, ah[g][r]);
        ah[g][r] = fmaf(hr[r].y, w.y, ah[g][r]);
        ah[g][r] = fmaf(hr[r].z, w.z, ah[g][r]);
        ah[g][r] = fmaf(hr[r].w, w.w, ah[g][r]);
      }
    }
  }
  {
    const int base = kq * 34 + jh;
#pragma unroll
    for (int g = 0; g < 3; ++g)
#pragma unroll
      for (int r = 0; r < 4; ++r) {
        gpart[(g * 4 + r) * 272 + base] = ai[g][r];
        gpart[(12 + g * 4 + r) * 272 + base] = ah[g][r];
      }
  }
  __syncthreads();

  if (tid < 128) {
    const int r = tid >> 5, jh2 = tid & 31;
    const int j2 = j0 + jh2;
    float g6[6];
#pragma unroll
    for (int c = 0; c < 6; ++c) {
      const int cc = (c < 3) ? (c * 4 + r) : (12 + (c - 3) * 4 + r);
      float s = 0.0f;
#pragma unroll
      for (int q = 0; q < 8; ++q) s += gpart[cc * 272 + q * 34 + jh2];
      g6[c] = s;
    }
    const float ir = g6[0] + b_ih[j2];
    const float iz = g6[1] + b_ih[HH + j2];
    const float in_ = g6[2] + b_ih[2 * HH + j2];
    const float hr_ = g6[3] + b_hh[j2];
    const float hz = g6[4] + b_hh[HH + j2];
    const float hn = g6[5] + b_hh[2 * HH + j2];
    const float rr = 1.0f / (1.0f + expf(-(ir + hr_)));
    const float zz = 1.0f / (1.0f + expf(-(iz + hz)));
    const float nn = tanhf(in_ + rr * hn);
    hout[(r0 + r) * HH + j2] = (1.0f - zz) * nn + zz * hsm[r][j2];
  }
}

// ---------------------------------------------------------------------------
// Full-output writer: one-hot rows composed inline (no memset), h x3,
// scores x3. All stores float4, coalesced.
// ---------------------------------------------------------------------------
__global__ __launch_bounds__(256) void k_out(
    const int* __restrict__ tok_seq, const float* __restrict__ hfin,
    const float* __restrict__ scores, float* __restrict__ out) {
  const int blk = blockIdx.x, tid = threadIdx.x;
  if (blk < BB * (TSTEPS + 1)) {           // one (b,t) one-hot row
    const int b = blk / (TSTEPS + 1), t = blk % (TSTEPS + 1);
    const int tok = tok_seq[t * BB + b];
    const int tq = tok >> 2, tl = tok & 3;
    float4* op = (float4*)(out + (size_t)blk * VV);
    for (int i = tid; i < VV / 4; i += 256) {
      float4 z = {0.0f, 0.0f, 0.0f, 0.0f};
      if (i == tq) (&z.x)[tl] = 1.0f;
      op[i] = z;
    }
  } else if (blk < BB * (TSTEPS + 1) + 12) {  // h x3: 12288 float4
#pragma unroll
    for (int it = 0; it < 4; ++it) {
      const int idx = (blk - BB * (TSTEPS + 1)) * 1024 + it * 256 + tid;
      if (idx < H_ELEMS / 4) {
        const int fi = idx * 4;
        const int b = fi / (3 * HH);
        const int j0 = (fi % (3 * HH)) % HH;
        ((float4*)(out + DEC_ELEMS))[idx] =
            *(const float4*)(hfin + b * HH + j0);
      }
    }
  } else {                                   // scores x3: 96 floats
    if (tid < BB * 3) {
      out[(size_t)DEC_ELEMS + H_ELEMS + tid] = scores[tid / 3];
    }
  }
}

// ---------------------------------------------------------------------------
extern "C" void kernel_launch(void* const* d_in, const int* in_sizes, int n_in,
                              void* d_out, int out_size, void* d_ws, size_t ws_size,
                              hipStream_t stream) {
  const float* enc_h = (const float*)d_in[1];
  const float* emb   = (const float*)d_in[2];
  const float* W_ih  = (const float*)d_in[3];
  const float* W_hh  = (const float*)d_in[4];
  const float* b_ih  = (const float*)d_in[5];
  const float* b_hh  = (const float*)d_in[6];
  const float* W_out = (const float*)d_in[7];
  const float* b_out = (const float*)d_in[8];
  float* out = (float*)d_out;

  // workspace layout (floats) — ~65.9 MB total
  float* ws = (float*)d_ws;
  float* Wt_out  = ws;                       // 16,384,000
  float* hb0     = Wt_out + 16384000;        // 16,384
  float* hb1     = hb0 + BB * HH;            // 16,384
  float* pm      = hb1 + BB * HH;            // 32*512
  float* ps      = pm + BB * PSTR;           // 32*512
  float* scores  = ps + BB * PSTR;           // 32
  int*   pidx    = (int*)(scores + BB);      // 32*512
  int*   tok_seq = pidx + BB * PSTR;         // 33*32

  k_transpose_out<<<dim3(1000, 16), 256, 0, stream>>>(W_out, Wt_out);
  k_init<<<64, 256, 0, stream>>>(enc_h, hb0, scores, tok_seq);

  for (int t = 0; t < TSTEPS; ++t) {
    float* hin  = (t & 1) ? hb1 : hb0;
    float* hout = (t & 1) ? hb0 : hb1;
    k_gru<<<128, 256, 0, stream>>>(t, emb, W_ih, W_hh, b_ih, b_hh,
                                   hin, hout, pm, ps, pidx, scores, tok_seq);
    k_gemv_fused<<<NCH, 256, 0, stream>>>(Wt_out, hout, b_out, pm, ps, pidx);
  }
  // final selection: seq col 32 + last score term
  k_gru<<<128, 256, 0, stream>>>(TSTEPS, emb, W_ih, W_hh, b_ih, b_hh,
                                 hb0, hb1, pm, ps, pidx, scores, tok_seq);
  // final h lives in hb0 (t=31 odd: hout=hb0); full-output writer
  k_out<<<BB * (TSTEPS + 1) + 13, 256, 0, stream>>>(tok_seq, hb0, scores, out);
}